// Round 1
// baseline (5200.870 us; speedup 1.0000x reference)
//
#include <hip/hip_runtime.h>
#include <hip/hip_bf16.h>
#include <cstdint>

// Seq2Seq LSTM: B=2048, H=512, I=64, T_enc=256, T_dec=10.
// Strategy: per-step fused GEMM+LSTM-cell kernel. gates = [x|h]@[Wih|Whh]^T with
// MFMA bf16 (fp32 accum). Precision: x and Wih in bf16 hi+lo (3 K-blocks),
// h and Whh plain bf16, c kept fp32. Packed K' = 64*3 + 512 = 704.
// Weight rows permuted gate-interleaved so the epilogue has i,f,g,o in-lane.

#define B_    2048
#define H_    512
#define I_    64
#define TENC  256
#define TDEC  10
#define NP    2048   // 4*H
#define KP    704    // packed K
#define NKB   11     // K-blocks of 64

typedef __bf16 bf16x8 __attribute__((ext_vector_type(8)));
typedef float  f32x4  __attribute__((ext_vector_type(4)));
typedef unsigned int   u32;
typedef unsigned short u16;

__device__ __forceinline__ u16 f2bf_rne(float f){
  u32 b = __float_as_uint(f);
  b += 0x7FFFu + ((b >> 16) & 1u);
  return (u16)(b >> 16);
}
__device__ __forceinline__ float bf2f(u16 u){ return __uint_as_float(((u32)u) << 16); }

__device__ __forceinline__ void gl_lds16(const void* g, void* l){
  __builtin_amdgcn_global_load_lds((const __attribute__((address_space(1))) u32*)g,
                                   (__attribute__((address_space(3))) u32*)l, 16, 0, 0);
}

__device__ __forceinline__ float sigm(float x){ return 1.f / (1.f + __expf(-x)); }
__device__ __forceinline__ float tanhfast(float x){ return 1.f - 2.f / (1.f + __expf(2.f * x)); }

// ---------------------------------------------------------------------------
// Weight packing: Wpk[np][col], np = gate-interleaved permutation of 4H rows.
// np = nt*128 + nh*64 + g*16 + jl  ->  original row n = g*512 + (nt*2+nh)*16 + jl
// cols: [0,64)=Wih_hi  [64,128)=Wih_lo  [128,192)=Wih_hi(dup)  [192,704)=Whh bf16
// ---------------------------------------------------------------------------
__global__ __launch_bounds__(256) void pack_lstm_weights(
    const float* __restrict__ Wih, const float* __restrict__ Whh,
    const float* __restrict__ bih, const float* __restrict__ bhh,
    u16* __restrict__ Wpk, float* __restrict__ bias_pk)
{
  int idx = blockIdx.x * 256 + threadIdx.x;
  if (idx >= NP * KP) return;
  int np = idx / KP, col = idx - np * KP;
  int nt = np >> 7, nh = (np >> 6) & 1, g = (np >> 4) & 3, jl = np & 15;
  int n = g * H_ + ((nt * 2 + nh) << 4) + jl;
  u16 outv;
  if (col < 64) {
    outv = f2bf_rne(Wih[n * 64 + col]);
  } else if (col < 128) {
    float w = Wih[n * 64 + col - 64];
    u16 h = f2bf_rne(w);
    outv = f2bf_rne(w - bf2f(h));
  } else if (col < 192) {
    outv = f2bf_rne(Wih[n * 64 + col - 128]);
  } else {
    outv = f2bf_rne(Whh[(size_t)n * H_ + (col - 192)]);
  }
  Wpk[idx] = outv;
  if (col == 0) bias_pk[np] = bih[n] + bhh[n];
}

__global__ __launch_bounds__(256) void transpose_wd(const float* __restrict__ Wd,
                                                    float* __restrict__ WdT)
{
  int idx = blockIdx.x * 256 + threadIdx.x;   // over 64*512 (I,H) row-major
  if (idx >= I_ * H_) return;
  int n = idx >> 9, k = idx & 511;
  WdT[k * 64 + n] = Wd[idx];
}

// ---------------------------------------------------------------------------
// One LSTM step: gates = x_t@Wih^T(+hi/lo) + h@Whh^T + bias; cell update fused.
// Grid 256 (16x16 tiles of 128x128), block 256 (4 waves, 64x64 each).
// LDS: A[128][64] (xhi then h-blocks), W[128][64], XLO[128][64]; XOR-swizzled
// by ((row&7)<<4) on the 16B chunk; global_load_lds sources pre-unswizzled.
// ---------------------------------------------------------------------------
__global__ __launch_bounds__(256) void lstm_step(
    const float* __restrict__ xsrc, int xstride,
    const u16* __restrict__ h_in,
    const u16* __restrict__ Wpk,
    const float* __restrict__ bias_pk,
    float* __restrict__ c_buf,
    u16* __restrict__ h_out,
    float* __restrict__ h_f32, int write_hf32)
{
  __shared__ __align__(16) char smem[49152];
  const int AOFF = 0, WOFF = 16384, XLO = 32768;
  int tid = threadIdx.x;
  int bid = blockIdx.x;
  int sw = ((bid & 7) << 5) | (bid >> 3);   // XCD-contiguous swizzle (256 = 8*32)
  int mt = sw >> 4, nt = sw & 15;

  // --- convert x_t tile fp32 -> (xhi in AOFF, xlo in XLO), swizzled writes ---
  {
    int r = tid >> 1, hf = tid & 1;
    const float* xp = xsrc + (size_t)(mt * 128 + r) * xstride + hf * 32;
    float v[32];
    #pragma unroll
    for (int q = 0; q < 8; ++q) {
      float4 f = ((const float4*)xp)[q];
      v[q*4] = f.x; v[q*4+1] = f.y; v[q*4+2] = f.z; v[q*4+3] = f.w;
    }
    #pragma unroll
    for (int q = 0; q < 4; ++q) {
      u32 hv[4], lv[4];
      #pragma unroll
      for (int e = 0; e < 4; ++e) {
        float f0 = v[q*8 + e*2], f1 = v[q*8 + e*2 + 1];
        u16 h0 = f2bf_rne(f0), h1 = f2bf_rne(f1);
        u16 l0 = f2bf_rne(f0 - bf2f(h0)), l1 = f2bf_rne(f1 - bf2f(h1));
        hv[e] = (u32)h0 | ((u32)h1 << 16);
        lv[e] = (u32)l0 | ((u32)l1 << 16);
      }
      int c = hf * 4 + q, sc = c ^ (r & 7);
      *(uint4*)(smem + AOFF + r * 128 + sc * 16) = make_uint4(hv[0], hv[1], hv[2], hv[3]);
      *(uint4*)(smem + XLO  + r * 128 + sc * 16) = make_uint4(lv[0], lv[1], lv[2], lv[3]);
    }
  }

  int wid = tid >> 6, lane = tid & 63;
  int mh = wid >> 1, nh = wid & 1;
  int lr = lane & 15, lgp = lane >> 4;

  f32x4 acc[4][4];
  #pragma unroll
  for (int a = 0; a < 4; ++a)
    #pragma unroll
    for (int b = 0; b < 4; ++b) acc[a][b] = (f32x4){0.f, 0.f, 0.f, 0.f};

  int rloc = tid >> 3, ch = tid & 7;   // staging: row-in-32, 16B chunk

  for (int kb = 0; kb < NKB; ++kb) {
    // stage W block (always)
    {
      const u16* wb = Wpk + (size_t)(nt * 128) * KP + kb * 64;
      #pragma unroll
      for (int rd = 0; rd < 4; ++rd) {
        int row = rd * 32 + rloc;
        int sc = ch ^ (row & 7);
        gl_lds16(wb + (size_t)row * KP + sc * 8, smem + WOFF + rd * 4096 + tid * 16);
      }
    }
    // stage A block from h (kb>=3); kb 0..2 use the x tiles already in LDS
    if (kb >= 3) {
      const u16* ab = h_in + (size_t)(mt * 128) * H_ + (kb - 3) * 64;
      #pragma unroll
      for (int rd = 0; rd < 4; ++rd) {
        int row = rd * 32 + rloc;
        int sc = ch ^ (row & 7);
        gl_lds16(ab + (size_t)row * H_ + sc * 8, smem + AOFF + rd * 4096 + tid * 16);
      }
    }
    __syncthreads();
    int ab_off = (kb == 2) ? XLO : AOFF;
    #pragma unroll
    for (int ks = 0; ks < 2; ++ks) {
      bf16x8 af[4], bfr[4];
      #pragma unroll
      for (int mi = 0; mi < 4; ++mi) {
        int row = mh * 64 + mi * 16 + lr;
        int c = ks * 4 + lgp;
        af[mi] = *(const bf16x8*)(smem + ab_off + row * 128 + ((c ^ (row & 7)) << 4));
      }
      #pragma unroll
      for (int ni = 0; ni < 4; ++ni) {
        int row = nh * 64 + ni * 16 + lr;
        int c = ks * 4 + lgp;
        bfr[ni] = *(const bf16x8*)(smem + WOFF + row * 128 + ((c ^ (row & 7)) << 4));
      }
      #pragma unroll
      for (int mi = 0; mi < 4; ++mi)
        #pragma unroll
        for (int ni = 0; ni < 4; ++ni)
          acc[mi][ni] = __builtin_amdgcn_mfma_f32_16x16x32_bf16(af[mi], bfr[ni], acc[mi][ni], 0, 0, 0);
    }
    __syncthreads();
  }

  // --- fused LSTM cell epilogue: gates i,f,g,o are acc[mi][0..3], same lane ---
  float bI = bias_pk[nt * 128 + nh * 64 +  0 + lr];
  float bF = bias_pk[nt * 128 + nh * 64 + 16 + lr];
  float bG = bias_pk[nt * 128 + nh * 64 + 32 + lr];
  float bO = bias_pk[nt * 128 + nh * 64 + 48 + lr];
  int j = ((nt * 2 + nh) << 4) + lr;   // hidden-unit index in [0,512)
  #pragma unroll
  for (int mi = 0; mi < 4; ++mi) {
    #pragma unroll
    for (int rr = 0; rr < 4; ++rr) {
      int row = mt * 128 + mh * 64 + mi * 16 + lgp * 4 + rr;
      size_t idx = (size_t)row * H_ + j;
      float gi = acc[mi][0][rr] + bI;
      float gf = acc[mi][1][rr] + bF;
      float gg = acc[mi][2][rr] + bG;
      float go = acc[mi][3][rr] + bO;
      float cold = c_buf[idx];
      float cn = sigm(gf) * cold + sigm(gi) * tanhfast(gg);
      float hn = sigm(go) * tanhfast(cn);
      c_buf[idx] = cn;
      h_out[idx] = f2bf_rne(hn);
      if (write_hf32) h_f32[idx] = hn;
    }
  }
}

// ---------------------------------------------------------------------------
// Decoder projection: dec_out = h@lin_dec_W^T + b (fp32), y = dec_out@lin_out^T + b
// One block (64 threads = 1 wave) per batch row; WdT gives coalesced loads.
// ---------------------------------------------------------------------------
__global__ __launch_bounds__(64) void dec_proj(
    const float* __restrict__ h_f32, const float* __restrict__ WdT,
    const float* __restrict__ ldb, const float* __restrict__ Wout,
    const float* __restrict__ bout, float* __restrict__ dec_out,
    float* __restrict__ out, int tdec)
{
  int b = blockIdx.x, n = threadIdx.x;
  const float* hr = h_f32 + (size_t)b * H_;
  float acc = ldb[n];
  #pragma unroll 8
  for (int k = 0; k < H_; ++k) acc += hr[k] * WdT[k * 64 + n];
  dec_out[(size_t)b * 64 + n] = acc;
  float yv = acc * Wout[n];
  #pragma unroll
  for (int off = 32; off > 0; off >>= 1) yv += __shfl_xor(yv, off, 64);
  if (n == 0) out[b * TDEC + tdec] = yv + bout[0];
}

// ---------------------------------------------------------------------------
extern "C" void kernel_launch(void* const* d_in, const int* in_sizes, int n_in,
                              void* d_out, int out_size, void* d_ws, size_t ws_size,
                              hipStream_t stream)
{
  const float* x    = (const float*)d_in[0];
  const float* eWih = (const float*)d_in[1];
  const float* eWhh = (const float*)d_in[2];
  const float* ebih = (const float*)d_in[3];
  const float* ebhh = (const float*)d_in[4];
  const float* dWih = (const float*)d_in[5];
  const float* dWhh = (const float*)d_in[6];
  const float* dbih = (const float*)d_in[7];
  const float* dbhh = (const float*)d_in[8];
  const float* ldW  = (const float*)d_in[9];
  const float* ldb  = (const float*)d_in[10];
  const float* loW  = (const float*)d_in[11];
  const float* lob  = (const float*)d_in[12];
  float* out = (float*)d_out;

  char* ws = (char*)d_ws;
  size_t o = 0;
  auto alloc = [&](size_t bytes){ size_t r = o; o += (bytes + 255) & ~(size_t)255; return r; };
  u16*   WpkE  = (u16*)  (ws + alloc((size_t)NP * KP * 2));
  u16*   WpkD  = (u16*)  (ws + alloc((size_t)NP * KP * 2));
  float* biasE = (float*)(ws + alloc((size_t)NP * 4));
  float* biasD = (float*)(ws + alloc((size_t)NP * 4));
  float* WdT   = (float*)(ws + alloc((size_t)I_ * H_ * 4));
  u16*   hb0   = (u16*)  (ws + alloc((size_t)B_ * H_ * 2));
  u16*   hb1   = (u16*)  (ws + alloc((size_t)B_ * H_ * 2));
  float* cbuf  = (float*)(ws + alloc((size_t)B_ * H_ * 4));
  float* hf32  = (float*)(ws + alloc((size_t)B_ * H_ * 4));
  float* dout  = (float*)(ws + alloc((size_t)B_ * I_ * 4));
  (void)ws_size; (void)in_sizes; (void)n_in; (void)out_size;

  int packBlocks = (NP * KP + 255) / 256;
  pack_lstm_weights<<<packBlocks, 256, 0, stream>>>(eWih, eWhh, ebih, ebhh, WpkE, biasE);
  pack_lstm_weights<<<packBlocks, 256, 0, stream>>>(dWih, dWhh, dbih, dbhh, WpkD, biasD);
  transpose_wd<<<(I_ * H_ + 255) / 256, 256, 0, stream>>>(ldW, WdT);
  hipMemsetAsync(hb0, 0, (size_t)B_ * H_ * 2, stream);
  hipMemsetAsync(cbuf, 0, (size_t)B_ * H_ * 4, stream);

  u16* hb[2] = {hb0, hb1};
  for (int t = 0; t < TENC; ++t) {
    lstm_step<<<256, 256, 0, stream>>>(x + (size_t)t * 64, 256 * 64,
                                       hb[t & 1], WpkE, biasE, cbuf,
                                       hb[(t + 1) & 1], (float*)nullptr, 0);
  }
  for (int d = 0; d < TDEC; ++d) {
    const float* src = (d == 0) ? (x + (size_t)255 * 64) : dout;
    int xstride = (d == 0) ? 256 * 64 : 64;
    lstm_step<<<256, 256, 0, stream>>>(src, xstride,
                                       hb[d & 1], WpkD, biasD, cbuf,
                                       hb[(d + 1) & 1], hf32, 1);
    dec_proj<<<B_, 64, 0, stream>>>(hf32, WdT, ldb, loW, lob, dout, out, d);
  }
}